// Round 3
// baseline (1715.181 us; speedup 1.0000x reference)
//
#include <hip/hip_runtime.h>
#include <math.h>

#define NL 16
#define HASH_SIZE (1u << 19)
#define HASH_MASK (HASH_SIZE - 1u)
#define P1 2654435761u
#define P2 805459861u
#define PTS_PER_BLOCK 1024
#define THREADS 256

typedef float f2 __attribute__((ext_vector_type(2)));
typedef float f4 __attribute__((ext_vector_type(4)));

struct Res16 { float r[NL]; };

// ---- shared per-(point,level) math: 8 hash gathers + trilinear blend ----
__device__ __forceinline__ f2 enc_pl(const f2* __restrict__ tb, float r,
                                     float px, float py, float pz)
{
    float sx = px * r, sy = py * r, sz = pz * r;
    float fx = floorf(sx), fy = floorf(sy), fz = floorf(sz);
    float wx = sx - fx, wy = sy - fy, wz = sz - fz;
    unsigned ix = (unsigned)(int)fx;
    unsigned iy = (unsigned)(int)fy;
    unsigned iz = (unsigned)(int)fz;
    // per-dim hash partials; uint32 wrap matches reference exactly
    unsigned hx0 = ix,      hx1 = ix + 1u;
    unsigned hy0 = iy * P1, hy1 = hy0 + P1;
    unsigned hz0 = iz * P2, hz1 = hz0 + P2;

    f2 f000 = tb[(hx0 ^ hy0 ^ hz0) & HASH_MASK];
    f2 f001 = tb[(hx0 ^ hy0 ^ hz1) & HASH_MASK];
    f2 f010 = tb[(hx0 ^ hy1 ^ hz0) & HASH_MASK];
    f2 f011 = tb[(hx0 ^ hy1 ^ hz1) & HASH_MASK];
    f2 f100 = tb[(hx1 ^ hy0 ^ hz0) & HASH_MASK];
    f2 f101 = tb[(hx1 ^ hy0 ^ hz1) & HASH_MASK];
    f2 f110 = tb[(hx1 ^ hy1 ^ hz0) & HASH_MASK];
    f2 f111 = tb[(hx1 ^ hy1 ^ hz1) & HASH_MASK];

    float wx0 = 1.0f - wx, wy0 = 1.0f - wy, wz0 = 1.0f - wz;
    float c000 = (wx0 * wy0) * wz0, c001 = (wx0 * wy0) * wz;
    float c010 = (wx0 * wy ) * wz0, c011 = (wx0 * wy ) * wz;
    float c100 = (wx  * wy0) * wz0, c101 = (wx  * wy0) * wz;
    float c110 = (wx  * wy ) * wz0, c111 = (wx  * wy ) * wz;

    float a0 = c000 * f000.x + c001 * f001.x + c010 * f010.x + c011 * f011.x
             + c100 * f100.x + c101 * f101.x + c110 * f110.x + c111 * f111.x;
    float a1 = c000 * f000.y + c001 * f001.y + c010 * f010.y + c011 * f011.y
             + c100 * f100.y + c101 * f101.y + c110 * f110.y + c111 * f111.y;
    f2 ret; ret.x = a0; ret.y = a1;
    return ret;
}

// ---- pass 1: one level per block; level = phase*8 + blockIdx%8 so each XCD
// (round-robin mod 8) sees exactly one 4MB table at a time -> L2-resident ----
__global__ __launch_bounds__(THREADS) void hashenc_level_kernel(
    const float* __restrict__ x,
    const float* __restrict__ tables,
    float* __restrict__ ws,          // [NL][N][2] level-major
    int N, int nchunks, Res16 res)
{
    int slot  = blockIdx.x & 7;
    int rest  = blockIdx.x >> 3;
    int chunk = rest % nchunks;
    int phase = rest / nchunks;      // 0: levels 0-7, 1: levels 8-15
    int level = phase * 8 + slot;

    float r = res.r[level];
    const f2* __restrict__ tb =
        reinterpret_cast<const f2*>(tables) + (size_t)level * HASH_SIZE;
    f2* __restrict__ wl =
        reinterpret_cast<f2*>(ws) + (size_t)level * N;

    int base = chunk * PTS_PER_BLOCK + threadIdx.x;
#pragma unroll
    for (int i = 0; i < PTS_PER_BLOCK / THREADS; ++i) {
        int n = base + i * THREADS;
        if (n >= N) break;
        // non-temporal x reads: don't let the 24MB x stream evict table lines
        float px = __builtin_nontemporal_load(x + 3 * (size_t)n + 0);
        float py = __builtin_nontemporal_load(x + 3 * (size_t)n + 1);
        float pz = __builtin_nontemporal_load(x + 3 * (size_t)n + 2);
        px = fminf(fmaxf(px, 0.0f), 0.999999f);
        py = fminf(fmaxf(py, 0.0f), 0.999999f);
        pz = fminf(fmaxf(pz, 0.0f), 0.999999f);
        f2 a = enc_pl(tb, r, px, py, pz);
        __builtin_nontemporal_store(a, wl + n);   // coalesced full lines
    }
}

// ---- pass 2: level-major ws -> point-major out; 2 points/thread so each ws
// read is a float4 and each thread writes 256B contiguous ----
__global__ __launch_bounds__(THREADS) void hashenc_gather_kernel(
    const float* __restrict__ ws, float* __restrict__ out, int N)
{
    int t  = blockIdx.x * THREADS + threadIdx.x;
    int p0 = 2 * t;
    if (p0 >= N) return;
    float r0[2 * NL], r1[2 * NL];
#pragma unroll
    for (int l = 0; l < NL; ++l) {
        f4 v = __builtin_nontemporal_load(
            reinterpret_cast<const f4*>(ws + (size_t)l * N * 2 + (size_t)p0 * 2));
        r0[2 * l] = v.x; r0[2 * l + 1] = v.y;
        r1[2 * l] = v.z; r1[2 * l + 1] = v.w;
    }
    f4* o0 = reinterpret_cast<f4*>(out + (size_t)p0 * (2 * NL));
#pragma unroll
    for (int q = 0; q < 8; ++q) {
        f4 v; v.x = r0[4*q]; v.y = r0[4*q+1]; v.z = r0[4*q+2]; v.w = r0[4*q+3];
        __builtin_nontemporal_store(v, o0 + q);
    }
    if (p0 + 1 < N) {
        f4* o1 = reinterpret_cast<f4*>(out + (size_t)(p0 + 1) * (2 * NL));
#pragma unroll
        for (int q = 0; q < 8; ++q) {
            f4 v; v.x = r1[4*q]; v.y = r1[4*q+1]; v.z = r1[4*q+2]; v.w = r1[4*q+3];
            __builtin_nontemporal_store(v, o1 + q);
        }
    }
}

// ---- fallback (round-1 monolithic) if ws is too small ----
__global__ __launch_bounds__(THREADS) void hashenc_mono_kernel(
    const float* __restrict__ x, const float* __restrict__ tables,
    float* __restrict__ out, int N, Res16 res)
{
    int n = blockIdx.x * THREADS + threadIdx.x;
    if (n >= N) return;
    float px = x[3 * (size_t)n + 0], py = x[3 * (size_t)n + 1], pz = x[3 * (size_t)n + 2];
    px = fminf(fmaxf(px, 0.0f), 0.999999f);
    py = fminf(fmaxf(py, 0.0f), 0.999999f);
    pz = fminf(fmaxf(pz, 0.0f), 0.999999f);
    float acc[2 * NL];
#pragma unroll
    for (int l = 0; l < NL; ++l) {
        const f2* tb = reinterpret_cast<const f2*>(tables) + (size_t)l * HASH_SIZE;
        f2 a = enc_pl(tb, res.r[l], px, py, pz);
        acc[2 * l] = a.x; acc[2 * l + 1] = a.y;
    }
    f4* o = reinterpret_cast<f4*>(out + (size_t)n * (2 * NL));
#pragma unroll
    for (int q = 0; q < 8; ++q) {
        f4 v; v.x = acc[4*q]; v.y = acc[4*q+1]; v.z = acc[4*q+2]; v.w = acc[4*q+3];
        o[q] = v;
    }
}

extern "C" void kernel_launch(void* const* d_in, const int* in_sizes, int n_in,
                              void* d_out, int out_size, void* d_ws, size_t ws_size,
                              hipStream_t stream)
{
    const float* x      = (const float*)d_in[0];
    const float* tables = (const float*)d_in[1];
    float* out          = (float*)d_out;
    int N = in_sizes[0] / 3;

    // Replicate numpy's resolutions bit-for-bit with glibc doubles (levels
    // 3/6/9/12/15 sit on exact ceil boundaries -> must compute, not guess).
    Res16 res;
    double b = exp((log(512.0) - log(16.0)) / 15.0);
    for (int i = 0; i < NL; ++i)
        res.r[i] = (float)(int)ceil(16.0 * pow(b, (double)i));

    size_t ws_need = (size_t)NL * (size_t)N * 2 * sizeof(float);
    if (ws_size >= ws_need) {
        int nchunks = (N + PTS_PER_BLOCK - 1) / PTS_PER_BLOCK;
        int gridA = 2 * 8 * nchunks;   // phase-major: levels 0-7 then 8-15
        hipLaunchKernelGGL(hashenc_level_kernel, dim3(gridA), dim3(THREADS), 0, stream,
                           x, tables, (float*)d_ws, N, nchunks, res);
        int gridB = ((N + 1) / 2 + THREADS - 1) / THREADS;
        hipLaunchKernelGGL(hashenc_gather_kernel, dim3(gridB), dim3(THREADS), 0, stream,
                           (const float*)d_ws, out, N);
    } else {
        int grid = (N + THREADS - 1) / THREADS;
        hipLaunchKernelGGL(hashenc_mono_kernel, dim3(grid), dim3(THREADS), 0, stream,
                           x, tables, out, N, res);
    }
}

// Round 4
// 1104.967 us; speedup vs baseline: 1.5522x; 1.5522x over previous
//
#include <hip/hip_runtime.h>
#include <math.h>

#define NL 16
#define HASH_SIZE (1u << 19)
#define HASH_MASK (HASH_SIZE - 1u)
#define P1 2654435761u
#define P2 805459861u
#define PTS_PER_BLOCK 1024
#define THREADS 256

typedef float f2 __attribute__((ext_vector_type(2)));
typedef float f4 __attribute__((ext_vector_type(4)));

struct Res16 { float r[NL]; };

// ---- shared per-(point,level) math: 8 hash gathers + trilinear blend ----
__device__ __forceinline__ f2 enc_pl(const f2* __restrict__ tb, float r,
                                     float px, float py, float pz)
{
    float sx = px * r, sy = py * r, sz = pz * r;
    float fx = floorf(sx), fy = floorf(sy), fz = floorf(sz);
    float wx = sx - fx, wy = sy - fy, wz = sz - fz;
    unsigned ix = (unsigned)(int)fx;
    unsigned iy = (unsigned)(int)fy;
    unsigned iz = (unsigned)(int)fz;
    // per-dim hash partials; uint32 wrap matches reference exactly
    unsigned hx0 = ix,      hx1 = ix + 1u;
    unsigned hy0 = iy * P1, hy1 = hy0 + P1;
    unsigned hz0 = iz * P2, hz1 = hz0 + P2;

    f2 f000 = tb[(hx0 ^ hy0 ^ hz0) & HASH_MASK];
    f2 f001 = tb[(hx0 ^ hy0 ^ hz1) & HASH_MASK];
    f2 f010 = tb[(hx0 ^ hy1 ^ hz0) & HASH_MASK];
    f2 f011 = tb[(hx0 ^ hy1 ^ hz1) & HASH_MASK];
    f2 f100 = tb[(hx1 ^ hy0 ^ hz0) & HASH_MASK];
    f2 f101 = tb[(hx1 ^ hy0 ^ hz1) & HASH_MASK];
    f2 f110 = tb[(hx1 ^ hy1 ^ hz0) & HASH_MASK];
    f2 f111 = tb[(hx1 ^ hy1 ^ hz1) & HASH_MASK];

    float wx0 = 1.0f - wx, wy0 = 1.0f - wy, wz0 = 1.0f - wz;
    float c000 = (wx0 * wy0) * wz0, c001 = (wx0 * wy0) * wz;
    float c010 = (wx0 * wy ) * wz0, c011 = (wx0 * wy ) * wz;
    float c100 = (wx  * wy0) * wz0, c101 = (wx  * wy0) * wz;
    float c110 = (wx  * wy ) * wz0, c111 = (wx  * wy ) * wz;

    float a0 = c000 * f000.x + c001 * f001.x + c010 * f010.x + c011 * f011.x
             + c100 * f100.x + c101 * f101.x + c110 * f110.x + c111 * f111.x;
    float a1 = c000 * f000.y + c001 * f001.y + c010 * f010.y + c011 * f011.y
             + c100 * f100.y + c101 * f101.y + c110 * f110.y + c111 * f111.y;
    f2 ret; ret.x = a0; ret.y = a1;
    return ret;
}

// ---- pass 1 (UNCHANGED from round 3): one level per block; level =
// phase*8 + blockIdx%8 so each XCD (round-robin mod 8) sees exactly one
// 4MB table at a time -> L2-resident. FETCH proved this: 4.5GB -> 332MB. ----
__global__ __launch_bounds__(THREADS) void hashenc_level_kernel(
    const float* __restrict__ x,
    const float* __restrict__ tables,
    float* __restrict__ ws,          // [NL][N][2] level-major
    int N, int nchunks, Res16 res)
{
    int slot  = blockIdx.x & 7;
    int rest  = blockIdx.x >> 3;
    int chunk = rest % nchunks;
    int phase = rest / nchunks;      // 0: levels 0-7, 1: levels 8-15
    int level = phase * 8 + slot;

    float r = res.r[level];
    const f2* __restrict__ tb =
        reinterpret_cast<const f2*>(tables) + (size_t)level * HASH_SIZE;
    f2* __restrict__ wl =
        reinterpret_cast<f2*>(ws) + (size_t)level * N;

    int base = chunk * PTS_PER_BLOCK + threadIdx.x;
#pragma unroll
    for (int i = 0; i < PTS_PER_BLOCK / THREADS; ++i) {
        int n = base + i * THREADS;
        if (n >= N) break;
        // non-temporal x reads: don't let the 24MB x stream evict table lines
        float px = __builtin_nontemporal_load(x + 3 * (size_t)n + 0);
        float py = __builtin_nontemporal_load(x + 3 * (size_t)n + 1);
        float pz = __builtin_nontemporal_load(x + 3 * (size_t)n + 2);
        px = fminf(fmaxf(px, 0.0f), 0.999999f);
        py = fminf(fmaxf(py, 0.0f), 0.999999f);
        pz = fminf(fmaxf(pz, 0.0f), 0.999999f);
        f2 a = enc_pl(tb, r, px, py, pz);
        __builtin_nontemporal_store(a, wl + n);   // coalesced full lines
    }
}

// ---- pass 2 REWRITTEN: 8 lanes cooperate per point.
// Old version: each thread wrote 8xf4 at 256B stride -> every store instr
// touched 64 lines with 16B each (4x partial-line transactions) -> 710us.
// New: thread (c=tid&7, pid=tid>>3) reads levels 2c,2c+1 of point p (8B each;
// a wave's reads = 16 fully-used 64B segments) and writes ONE f4 at
// out[p*32+c*4]; a wave's stores = 1KB contiguous. ----
__global__ __launch_bounds__(THREADS) void hashenc_transpose_kernel(
    const float* __restrict__ ws, float* __restrict__ out, int N)
{
    int c    = threadIdx.x & 7;      // feature chunk -> levels 2c, 2c+1
    int pid  = threadIdx.x >> 3;     // 0..31
    int base = blockIdx.x * 256;     // 256 points per block
    const f2* __restrict__ w2 = reinterpret_cast<const f2*>(ws);
#pragma unroll
    for (int i = 0; i < 8; ++i) {
        int p = base + i * 32 + pid;
        if (p >= N) return;
        f2 a = __builtin_nontemporal_load(w2 + (size_t)(2 * c)     * N + p);
        f2 b = __builtin_nontemporal_load(w2 + (size_t)(2 * c + 1) * N + p);
        f4 v; v.x = a.x; v.y = a.y; v.z = b.x; v.w = b.y;
        __builtin_nontemporal_store(
            v, reinterpret_cast<f4*>(out + (size_t)p * (2 * NL) + c * 4));
    }
}

// ---- fallback (round-1 monolithic) if ws is too small ----
__global__ __launch_bounds__(THREADS) void hashenc_mono_kernel(
    const float* __restrict__ x, const float* __restrict__ tables,
    float* __restrict__ out, int N, Res16 res)
{
    int n = blockIdx.x * THREADS + threadIdx.x;
    if (n >= N) return;
    float px = x[3 * (size_t)n + 0], py = x[3 * (size_t)n + 1], pz = x[3 * (size_t)n + 2];
    px = fminf(fmaxf(px, 0.0f), 0.999999f);
    py = fminf(fmaxf(py, 0.0f), 0.999999f);
    pz = fminf(fmaxf(pz, 0.0f), 0.999999f);
    float acc[2 * NL];
#pragma unroll
    for (int l = 0; l < NL; ++l) {
        const f2* tb = reinterpret_cast<const f2*>(tables) + (size_t)l * HASH_SIZE;
        f2 a = enc_pl(tb, res.r[l], px, py, pz);
        acc[2 * l] = a.x; acc[2 * l + 1] = a.y;
    }
    f4* o = reinterpret_cast<f4*>(out + (size_t)n * (2 * NL));
#pragma unroll
    for (int q = 0; q < 8; ++q) {
        f4 v; v.x = acc[4*q]; v.y = acc[4*q+1]; v.z = acc[4*q+2]; v.w = acc[4*q+3];
        o[q] = v;
    }
}

extern "C" void kernel_launch(void* const* d_in, const int* in_sizes, int n_in,
                              void* d_out, int out_size, void* d_ws, size_t ws_size,
                              hipStream_t stream)
{
    const float* x      = (const float*)d_in[0];
    const float* tables = (const float*)d_in[1];
    float* out          = (float*)d_out;
    int N = in_sizes[0] / 3;

    // Replicate numpy's resolutions bit-for-bit with glibc doubles (levels
    // 3/6/9/12/15 sit on exact ceil boundaries -> must compute, not guess).
    Res16 res;
    double b = exp((log(512.0) - log(16.0)) / 15.0);
    for (int i = 0; i < NL; ++i)
        res.r[i] = (float)(int)ceil(16.0 * pow(b, (double)i));

    size_t ws_need = (size_t)NL * (size_t)N * 2 * sizeof(float);
    if (ws_size >= ws_need) {
        int nchunks = (N + PTS_PER_BLOCK - 1) / PTS_PER_BLOCK;
        int gridA = 2 * 8 * nchunks;   // phase-major: levels 0-7 then 8-15
        hipLaunchKernelGGL(hashenc_level_kernel, dim3(gridA), dim3(THREADS), 0, stream,
                           x, tables, (float*)d_ws, N, nchunks, res);
        int gridB = (N + 255) / 256;
        hipLaunchKernelGGL(hashenc_transpose_kernel, dim3(gridB), dim3(THREADS), 0, stream,
                           (const float*)d_ws, out, N);
    } else {
        int grid = (N + THREADS - 1) / THREADS;
        hipLaunchKernelGGL(hashenc_mono_kernel, dim3(grid), dim3(THREADS), 0, stream,
                           x, tables, out, N, res);
    }
}

// Round 5
// 1002.187 us; speedup vs baseline: 1.7114x; 1.1026x over previous
//
#include <hip/hip_runtime.h>
#include <math.h>

#define NL 16
#define HASH_SIZE (1u << 19)
#define HASH_MASK (HASH_SIZE - 1u)
#define P1 2654435761u
#define P2 805459861u
#define PTS_PER_BLOCK 1024
#define THREADS 256

typedef float f2 __attribute__((ext_vector_type(2)));
typedef float f4 __attribute__((ext_vector_type(4)));

struct Res16 { float r[NL]; };

// ---- per-(point,level): 8 hash gathers + trilinear blend.
// x-dim has prime 1, so for EVEN ix the two x-corners of each (j,k) pair are
// adjacent table entries sharing one aligned 16B word: idx(1,j,k)=idx(0,j,k)^1.
// -> 4 f4 gathers instead of 8 f2 gathers (-50% requests on even lanes,
// -25% average). Odd ix keeps the 8-load path. ----
__device__ __forceinline__ f2 enc_pl(const f2* __restrict__ tb, float r,
                                     float px, float py, float pz)
{
    float sx = px * r, sy = py * r, sz = pz * r;
    float fx = floorf(sx), fy = floorf(sy), fz = floorf(sz);
    float wx = sx - fx, wy = sy - fy, wz = sz - fz;
    unsigned ix = (unsigned)(int)fx;
    unsigned iy = (unsigned)(int)fy;
    unsigned iz = (unsigned)(int)fz;
    // per-dim hash partials; uint32 wrap matches reference exactly
    unsigned hy0 = iy * P1, hy1 = hy0 + P1;
    unsigned hz0 = iz * P2, hz1 = hz0 + P2;

    f2 f000, f001, f010, f011, f100, f101, f110, f111;

    if ((ix & 1u) == 0u) {
        // merged path: one aligned f4 covers corners (0,j,k) and (1,j,k)
        const f4* __restrict__ tb4 = reinterpret_cast<const f4*>(tb);
        unsigned g00 = (ix ^ hy0 ^ hz0) & HASH_MASK;
        unsigned g01 = (ix ^ hy0 ^ hz1) & HASH_MASK;
        unsigned g10 = (ix ^ hy1 ^ hz0) & HASH_MASK;
        unsigned g11 = (ix ^ hy1 ^ hz1) & HASH_MASK;
        f4 v00 = tb4[g00 >> 1];
        f4 v01 = tb4[g01 >> 1];
        f4 v10 = tb4[g10 >> 1];
        f4 v11 = tb4[g11 >> 1];
        f2 lo, hi;
        lo.x = v00.x; lo.y = v00.y; hi.x = v00.z; hi.y = v00.w;
        f000 = (g00 & 1u) ? hi : lo;  f100 = (g00 & 1u) ? lo : hi;
        lo.x = v01.x; lo.y = v01.y; hi.x = v01.z; hi.y = v01.w;
        f001 = (g01 & 1u) ? hi : lo;  f101 = (g01 & 1u) ? lo : hi;
        lo.x = v10.x; lo.y = v10.y; hi.x = v10.z; hi.y = v10.w;
        f010 = (g10 & 1u) ? hi : lo;  f110 = (g10 & 1u) ? lo : hi;
        lo.x = v11.x; lo.y = v11.y; hi.x = v11.z; hi.y = v11.w;
        f011 = (g11 & 1u) ? hi : lo;  f111 = (g11 & 1u) ? lo : hi;
    } else {
        unsigned hx0 = ix, hx1 = ix + 1u;
        f000 = tb[(hx0 ^ hy0 ^ hz0) & HASH_MASK];
        f001 = tb[(hx0 ^ hy0 ^ hz1) & HASH_MASK];
        f010 = tb[(hx0 ^ hy1 ^ hz0) & HASH_MASK];
        f011 = tb[(hx0 ^ hy1 ^ hz1) & HASH_MASK];
        f100 = tb[(hx1 ^ hy0 ^ hz0) & HASH_MASK];
        f101 = tb[(hx1 ^ hy0 ^ hz1) & HASH_MASK];
        f110 = tb[(hx1 ^ hy1 ^ hz0) & HASH_MASK];
        f111 = tb[(hx1 ^ hy1 ^ hz1) & HASH_MASK];
    }

    float wx0 = 1.0f - wx, wy0 = 1.0f - wy, wz0 = 1.0f - wz;
    float c000 = (wx0 * wy0) * wz0, c001 = (wx0 * wy0) * wz;
    float c010 = (wx0 * wy ) * wz0, c011 = (wx0 * wy ) * wz;
    float c100 = (wx  * wy0) * wz0, c101 = (wx  * wy0) * wz;
    float c110 = (wx  * wy ) * wz0, c111 = (wx  * wy ) * wz;

    // accumulation expression identical in both paths (bit-exact vs reference)
    float a0 = c000 * f000.x + c001 * f001.x + c010 * f010.x + c011 * f011.x
             + c100 * f100.x + c101 * f101.x + c110 * f110.x + c111 * f111.x;
    float a1 = c000 * f000.y + c001 * f001.y + c010 * f010.y + c011 * f011.y
             + c100 * f100.y + c101 * f101.y + c110 * f110.y + c111 * f111.y;
    f2 ret; ret.x = a0; ret.y = a1;
    return ret;
}

// ---- pass 1: one level per block; level = phase*8 + blockIdx%8 so each XCD
// (round-robin mod 8) sees exactly one 4MB table at a time -> L2-resident
// (proved: FETCH 4.5GB -> 332MB). ----
__global__ __launch_bounds__(THREADS) void hashenc_level_kernel(
    const float* __restrict__ x,
    const float* __restrict__ tables,
    float* __restrict__ ws,          // [NL][N][2] level-major
    int N, int nchunks, Res16 res)
{
    int slot  = blockIdx.x & 7;
    int rest  = blockIdx.x >> 3;
    int chunk = rest % nchunks;
    int phase = rest / nchunks;      // 0: levels 0-7, 1: levels 8-15
    int level = phase * 8 + slot;

    float r = res.r[level];
    const f2* __restrict__ tb =
        reinterpret_cast<const f2*>(tables) + (size_t)level * HASH_SIZE;
    f2* __restrict__ wl =
        reinterpret_cast<f2*>(ws) + (size_t)level * N;

    int base = chunk * PTS_PER_BLOCK + threadIdx.x;
#pragma unroll
    for (int i = 0; i < PTS_PER_BLOCK / THREADS; ++i) {
        int n = base + i * THREADS;
        if (n >= N) break;
        // non-temporal x reads: don't let the 24MB x stream evict table lines
        float px = __builtin_nontemporal_load(x + 3 * (size_t)n + 0);
        float py = __builtin_nontemporal_load(x + 3 * (size_t)n + 1);
        float pz = __builtin_nontemporal_load(x + 3 * (size_t)n + 2);
        px = fminf(fmaxf(px, 0.0f), 0.999999f);
        py = fminf(fmaxf(py, 0.0f), 0.999999f);
        pz = fminf(fmaxf(pz, 0.0f), 0.999999f);
        f2 a = enc_pl(tb, r, px, py, pz);
        __builtin_nontemporal_store(a, wl + n);   // coalesced full lines
    }
}

// ---- pass 2: 8 lanes cooperate per point; wave reads 16 coalesced 8B
// streams, writes 1KB contiguous (fixed the 4x partial-line stores). ----
__global__ __launch_bounds__(THREADS) void hashenc_transpose_kernel(
    const float* __restrict__ ws, float* __restrict__ out, int N)
{
    int c    = threadIdx.x & 7;      // feature chunk -> levels 2c, 2c+1
    int pid  = threadIdx.x >> 3;     // 0..31
    int base = blockIdx.x * 256;     // 256 points per block
    const f2* __restrict__ w2 = reinterpret_cast<const f2*>(ws);
#pragma unroll
    for (int i = 0; i < 8; ++i) {
        int p = base + i * 32 + pid;
        if (p >= N) return;
        f2 a = __builtin_nontemporal_load(w2 + (size_t)(2 * c)     * N + p);
        f2 b = __builtin_nontemporal_load(w2 + (size_t)(2 * c + 1) * N + p);
        f4 v; v.x = a.x; v.y = a.y; v.z = b.x; v.w = b.y;
        __builtin_nontemporal_store(
            v, reinterpret_cast<f4*>(out + (size_t)p * (2 * NL) + c * 4));
    }
}

// ---- fallback (monolithic) if ws is too small ----
__global__ __launch_bounds__(THREADS) void hashenc_mono_kernel(
    const float* __restrict__ x, const float* __restrict__ tables,
    float* __restrict__ out, int N, Res16 res)
{
    int n = blockIdx.x * THREADS + threadIdx.x;
    if (n >= N) return;
    float px = x[3 * (size_t)n + 0], py = x[3 * (size_t)n + 1], pz = x[3 * (size_t)n + 2];
    px = fminf(fmaxf(px, 0.0f), 0.999999f);
    py = fminf(fmaxf(py, 0.0f), 0.999999f);
    pz = fminf(fmaxf(pz, 0.0f), 0.999999f);
    float acc[2 * NL];
#pragma unroll
    for (int l = 0; l < NL; ++l) {
        const f2* tb = reinterpret_cast<const f2*>(tables) + (size_t)l * HASH_SIZE;
        f2 a = enc_pl(tb, res.r[l], px, py, pz);
        acc[2 * l] = a.x; acc[2 * l + 1] = a.y;
    }
    f4* o = reinterpret_cast<f4*>(out + (size_t)n * (2 * NL));
#pragma unroll
    for (int q = 0; q < 8; ++q) {
        f4 v; v.x = acc[4*q]; v.y = acc[4*q+1]; v.z = acc[4*q+2]; v.w = acc[4*q+3];
        o[q] = v;
    }
}

extern "C" void kernel_launch(void* const* d_in, const int* in_sizes, int n_in,
                              void* d_out, int out_size, void* d_ws, size_t ws_size,
                              hipStream_t stream)
{
    const float* x      = (const float*)d_in[0];
    const float* tables = (const float*)d_in[1];
    float* out          = (float*)d_out;
    int N = in_sizes[0] / 3;

    // Replicate numpy's resolutions bit-for-bit with glibc doubles (levels
    // 3/6/9/12/15 sit on exact ceil boundaries -> must compute, not guess).
    Res16 res;
    double b = exp((log(512.0) - log(16.0)) / 15.0);
    for (int i = 0; i < NL; ++i)
        res.r[i] = (float)(int)ceil(16.0 * pow(b, (double)i));

    size_t ws_need = (size_t)NL * (size_t)N * 2 * sizeof(float);
    if (ws_size >= ws_need) {
        int nchunks = (N + PTS_PER_BLOCK - 1) / PTS_PER_BLOCK;
        int gridA = 2 * 8 * nchunks;   // phase-major: levels 0-7 then 8-15
        hipLaunchKernelGGL(hashenc_level_kernel, dim3(gridA), dim3(THREADS), 0, stream,
                           x, tables, (float*)d_ws, N, nchunks, res);
        int gridB = (N + 255) / 256;
        hipLaunchKernelGGL(hashenc_transpose_kernel, dim3(gridB), dim3(THREADS), 0, stream,
                           (const float*)d_ws, out, N);
    } else {
        int grid = (N + THREADS - 1) / THREADS;
        hipLaunchKernelGGL(hashenc_mono_kernel, dim3(grid), dim3(THREADS), 0, stream,
                           x, tables, out, N, res);
    }
}